// Round 1
// baseline (1118.543 us; speedup 1.0000x reference)
//
#include <hip/hip_runtime.h>
#include <stdint.h>

constexpr int B = 4;
constexpr int N = 262144;
constexpr int C = 10;
constexpr int KPRE = 4096;
constexpr int KPOST = 500;
constexpr float ROI_THR = 0.1f;
constexpr float NMS_THR = 0.01f;
constexpr int CAP = 8192;       // compaction capacity (>= KPRE + boundary ties)
constexpr int MASKW = KPRE / 64; // 64 u64 words per mask row

__device__ __forceinline__ uint32_t f2k(float f) {
  uint32_t u = __float_as_uint(f);
  return (u & 0x80000000u) ? ~u : (u | 0x80000000u);
}
__device__ __forceinline__ float k2f(uint32_t k) {
  uint32_t u = (k & 0x80000000u) ? (k ^ 0x80000000u) : ~k;
  return __uint_as_float(u);
}
__device__ __forceinline__ float sigm(float x) { return 1.0f / (1.0f + expf(-x)); }

// ---------------- K0: scores -> sortable keys ----------------
__global__ void scoreK(const float* __restrict__ cls, uint32_t* __restrict__ keys) {
  int n = blockIdx.x * blockDim.x + threadIdx.x;
  int b = blockIdx.y;
  if (n >= N) return;
  const float* p = cls + ((size_t)b * N + n) * C;
  float m = sigm(p[0]);
#pragma unroll
  for (int c = 1; c < C; ++c) m = fmaxf(m, sigm(p[c]));
  float s = (m > ROI_THR) ? m : -1.0f;
  keys[(size_t)b * N + n] = f2k(s);
}

// ---------------- K1: init ----------------
__global__ void initK(uint32_t* hist, uint32_t* cnt, uint32_t* state, uint32_t* kept_cnt) {
  int t = threadIdx.x;
  for (int i = t; i < 4 * B * 256; i += blockDim.x) hist[i] = 0;
  if (t < B) {
    cnt[t] = 0;
    kept_cnt[t] = 0;
    state[t * 2 + 0] = 0;       // prefix
    state[t * 2 + 1] = KPRE;    // remaining rank
  }
}

// ---------------- K2: radix-select histogram pass P ----------------
template <int P>
__global__ void histK(const uint32_t* __restrict__ keys, const uint32_t* __restrict__ state,
                      uint32_t* __restrict__ hist) {
  __shared__ uint32_t h[256];
  int b = blockIdx.y;
  for (int i = threadIdx.x; i < 256; i += blockDim.x) h[i] = 0;
  __syncthreads();
  uint32_t pref = state[b * 2];
  constexpr int shift = 24 - 8 * P;
  const uint32_t* kb = keys + (size_t)b * N;
  for (int n = blockIdx.x * blockDim.x + threadIdx.x; n < N; n += gridDim.x * blockDim.x) {
    uint32_t k = kb[n];
    bool ok;
    if constexpr (P == 0) ok = true;
    else ok = (((k ^ pref) >> (8 * (4 - P))) == 0);
    if (ok) atomicAdd(&h[(k >> shift) & 255u], 1u);
  }
  __syncthreads();
  uint32_t* gh = hist + (P * B + b) * 256;
  for (int i = threadIdx.x; i < 256; i += blockDim.x)
    if (h[i]) atomicAdd(&gh[i], h[i]);
}

// ---------------- K3: radix-select scan pass P ----------------
template <int P>
__global__ void scanK(const uint32_t* __restrict__ hist, uint32_t* __restrict__ state) {
  int b = blockIdx.x;
  if (threadIdx.x != 0) return;
  const uint32_t* h = hist + (P * B + b) * 256;
  uint32_t R = state[b * 2 + 1];
  uint32_t cum = 0;
  int sel = 0;
  for (int bin = 255; bin >= 0; --bin) {
    uint32_t c = h[bin];
    if (cum + c >= R) { sel = bin; break; }
    cum += c;
  }
  constexpr int shift = 24 - 8 * P;
  state[b * 2 + 0] |= ((uint32_t)sel) << shift;
  state[b * 2 + 1] = R - cum;
}

// ---------------- K4: compact all keys >= T ----------------
__global__ void compactK(const uint32_t* __restrict__ keys, const uint32_t* __restrict__ state,
                         unsigned long long* __restrict__ list, uint32_t* __restrict__ cnt) {
  int b = blockIdx.y;
  uint32_t T = state[b * 2];
  const uint32_t* kb = keys + (size_t)b * N;
  for (int n = blockIdx.x * blockDim.x + threadIdx.x; n < N; n += gridDim.x * blockDim.x) {
    uint32_t k = kb[n];
    if (k >= T) {
      uint32_t pos = atomicAdd(&cnt[b], 1u);
      if (pos < CAP)
        list[(size_t)b * CAP + pos] = ((unsigned long long)k << 32) | (uint32_t)(~(uint32_t)n);
    }
  }
}

// ---------------- K5: bitonic sort (key desc, idx asc) + emit + gather boxes ----------------
__global__ __launch_bounds__(1024) void sortK(const unsigned long long* __restrict__ list,
                                              const uint32_t* __restrict__ cnt,
                                              const float* __restrict__ boxes,
                                              float* __restrict__ sel_score,
                                              uint32_t* __restrict__ sel_idx,
                                              float* __restrict__ sel_box) {
  __shared__ unsigned long long ls[CAP]; // 64 KiB
  int b = blockIdx.x;
  int t = threadIdx.x;
  uint32_t cc = min(cnt[b], (uint32_t)CAP);
  for (int i = t; i < CAP; i += 1024)
    ls[i] = (i < (int)cc) ? list[(size_t)b * CAP + i] : 0ull;
  __syncthreads();
  for (int k = 2; k <= CAP; k <<= 1) {
    for (int j = k >> 1; j > 0; j >>= 1) {
      for (int i = t; i < CAP; i += 1024) {
        int l = i ^ j;
        if (l > i) {
          unsigned long long a = ls[i], c = ls[l];
          bool desc = ((i & k) == 0);
          if ((a < c) == desc) { ls[i] = c; ls[l] = a; }
        }
      }
      __syncthreads();
    }
  }
  for (int i = t; i < KPRE; i += 1024) {
    unsigned long long p = ls[i];
    uint32_t key = (uint32_t)(p >> 32);
    uint32_t idx = ~(uint32_t)p;
    float sc;
    if (p == 0ull) { idx = 0; sc = -1.0f; } else sc = k2f(key);
    sel_score[b * KPRE + i] = sc;
    sel_idx[b * KPRE + i] = idx;
    const float* src = boxes + ((size_t)b * N + idx) * 7;
    float* dst = sel_box + ((size_t)b * KPRE + i) * 8;
#pragma unroll
    for (int c7 = 0; c7 < 7; ++c7) dst[c7] = src[c7];
    dst[7] = 0.f;
  }
}

// ---------------- K6: pairwise IoU suppression bitmask ----------------
__global__ void maskK(const float* __restrict__ sel_box, unsigned long long* __restrict__ mask) {
  __shared__ float jb[256][5];
  int b = blockIdx.y;
  int i = blockIdx.x * 256 + threadIdx.x;
  const float* myb = sel_box + ((size_t)b * KPRE + i) * 8;
  float x = myb[0], y = myb[1], dx = myb[3], dy = myb[4];
  float hx = __fmul_rn(dx, 0.5f), hy = __fmul_rn(dy, 0.5f);
  float x1i = __fsub_rn(x, hx), x2i = __fadd_rn(x, hx);
  float y1i = __fsub_rn(y, hy), y2i = __fadd_rn(y, hy);
  float ai = __fmul_rn(dx, dy);
  for (int jt = 0; jt < KPRE / 256; ++jt) {
    __syncthreads();
    {
      int jj = threadIdx.x;
      const float* bj = sel_box + ((size_t)b * KPRE + jt * 256 + jj) * 8;
      float xj = bj[0], yj = bj[1], dxj = bj[3], dyj = bj[4];
      float hxj = __fmul_rn(dxj, 0.5f), hyj = __fmul_rn(dyj, 0.5f);
      jb[jj][0] = __fsub_rn(xj, hxj);
      jb[jj][1] = __fadd_rn(xj, hxj);
      jb[jj][2] = __fsub_rn(yj, hyj);
      jb[jj][3] = __fadd_rn(yj, hyj);
      jb[jj][4] = __fmul_rn(dxj, dyj);
    }
    __syncthreads();
    unsigned long long w[4] = {0ull, 0ull, 0ull, 0ull};
    if (jt * 256 + 255 > i) {
      for (int jj = 0; jj < 256; ++jj) {
        int j = jt * 256 + jj;
        if (j <= i) continue;
        float xx1 = fmaxf(x1i, jb[jj][0]);
        float xx2 = fminf(x2i, jb[jj][1]);
        float yy1 = fmaxf(y1i, jb[jj][2]);
        float yy2 = fminf(y2i, jb[jj][3]);
        float ix = fmaxf(__fsub_rn(xx2, xx1), 0.0f);
        float iy = fmaxf(__fsub_rn(yy2, yy1), 0.0f);
        float inter = __fmul_rn(ix, iy);
        float uni = __fsub_rn(__fadd_rn(ai, jb[jj][4]), inter);
        float iou = inter / fmaxf(uni, 1e-6f);
        if (iou > NMS_THR) w[jj >> 6] |= 1ull << (jj & 63);
      }
    }
    unsigned long long* mrow = mask + ((size_t)b * KPRE + i) * MASKW + jt * 4;
#pragma unroll
    for (int q = 0; q < 4; ++q) mrow[q] = w[q];
  }
}

// ---------------- K7: serial greedy NMS scan (1 wave / batch) ----------------
__global__ void nmsK(const unsigned long long* __restrict__ mask,
                     const float* __restrict__ sel_score,
                     uint32_t* __restrict__ kept_pos, uint32_t* __restrict__ kept_cnt) {
  int b = blockIdx.x;
  int t = threadIdx.x; // 0..63, lane t owns bitmask word t
  unsigned long long cand = 0ull;
  for (int k = 0; k < 64; ++k) {
    float s = sel_score[b * KPRE + k * 64 + t];
    unsigned long long bal = __ballot(s > ROI_THR);
    if (t == k) cand = bal;
  }
  unsigned long long remv = 0ull;
  const unsigned long long* mb = mask + (size_t)b * KPRE * MASKW;
  unsigned long long r[8];
#pragma unroll
  for (int d = 0; d < 8; ++d) r[d] = mb[(size_t)d * MASKW + t];
  int kc = 0;
  for (int i0 = 0; i0 < KPRE; i0 += 8) {
#pragma unroll
    for (int d = 0; d < 8; ++d) {
      int i = i0 + d;
      int w = i >> 6, bit = i & 63;
      unsigned long long g = cand & ~remv;
      uint32_t half = (bit < 32) ? (uint32_t)g : (uint32_t)(g >> 32);
      uint32_t gw = (uint32_t)__shfl((int)half, w, 64);
      if ((gw >> (bit & 31)) & 1u) {
        remv |= r[d];
        if (t == 0 && kc < KPOST) kept_pos[b * KPOST + kc] = i;
        kc++;
      }
      int nx = i + 8;
      if (nx < KPRE) r[d] = mb[(size_t)nx * MASKW + t];
    }
    if (kc >= KPOST) break;
  }
  if (t == 0) kept_cnt[b] = (uint32_t)min(kc, KPOST);
}

// ---------------- K8: emit outputs ----------------
__global__ void outK(const float* __restrict__ cls,
                     const float* __restrict__ sel_score, const uint32_t* __restrict__ sel_idx,
                     const float* __restrict__ sel_box,
                     const uint32_t* __restrict__ kept_pos, const uint32_t* __restrict__ kept_cnt,
                     float* __restrict__ out) {
  int b = blockIdx.y;
  int s = blockIdx.x * blockDim.x + threadIdx.x;
  if (s >= KPOST) return;
  float* oS = out;                               // (B, KPOST)
  float* oB = out + B * KPOST;                   // (B, KPOST, 7)
  float* oL = out + B * KPOST + B * KPOST * 7;   // (B, KPOST)
  uint32_t kcnt = kept_cnt[b];
  if (s < (int)kcnt) {
    uint32_t pos = kept_pos[b * KPOST + s];
    oS[b * KPOST + s] = sel_score[b * KPRE + pos];
    const float* box = sel_box + ((size_t)b * KPRE + pos) * 8;
    float* dst = oB + ((size_t)b * KPOST + s) * 7;
#pragma unroll
    for (int c = 0; c < 7; ++c) dst[c] = box[c];
    uint32_t idx = sel_idx[b * KPRE + pos];
    const float* p = cls + ((size_t)b * N + idx) * C;
    float bestv = sigm(p[0]);
    int bestc = 0;
#pragma unroll
    for (int c = 1; c < C; ++c) {
      float v = sigm(p[c]);
      if (v > bestv) { bestv = v; bestc = c; }
    }
    oL[b * KPOST + s] = (float)bestc;
  } else {
    oS[b * KPOST + s] = 0.0f;
    float* dst = oB + ((size_t)b * KPOST + s) * 7;
#pragma unroll
    for (int c = 0; c < 7; ++c) dst[c] = 0.0f;
    oL[b * KPOST + s] = -1.0f;
  }
}

__global__ void sentinelK(float* out, int n) {
  int i = blockIdx.x * blockDim.x + threadIdx.x;
  if (i < n) out[i] = 1337.0f;
}

extern "C" void kernel_launch(void* const* d_in, const int* in_sizes, int n_in,
                              void* d_out, int out_size, void* d_ws, size_t ws_size,
                              hipStream_t stream) {
  const float* cls = (const float*)d_in[0];
  const float* boxes = (const float*)d_in[1];
  float* out = (float*)d_out;

  char* ws = (char*)d_ws;
  size_t off = 0;
  auto alloc = [&](size_t bytes) -> void* {
    void* p = ws + off;
    off = (off + bytes + 255) & ~(size_t)255;
    return p;
  };
  unsigned long long* mask = (unsigned long long*)alloc((size_t)B * KPRE * MASKW * 8);
  unsigned long long* list = (unsigned long long*)alloc((size_t)B * CAP * 8);
  uint32_t* keys = (uint32_t*)alloc((size_t)B * N * 4);
  float* sel_box = (float*)alloc((size_t)B * KPRE * 8 * 4);
  float* sel_score = (float*)alloc((size_t)B * KPRE * 4);
  uint32_t* sel_idx = (uint32_t*)alloc((size_t)B * KPRE * 4);
  uint32_t* hist = (uint32_t*)alloc(4 * B * 256 * 4);
  uint32_t* state = (uint32_t*)alloc(B * 2 * 4);
  uint32_t* cnt = (uint32_t*)alloc(B * 4);
  uint32_t* kept_pos = (uint32_t*)alloc(B * KPOST * 4);
  uint32_t* kept_cnt = (uint32_t*)alloc(B * 4);

  if (off > ws_size) {
    sentinelK<<<dim3((out_size + 255) / 256), 256, 0, stream>>>(out, out_size);
    return;
  }

  initK<<<1, 256, 0, stream>>>(hist, cnt, state, kept_cnt);
  scoreK<<<dim3(N / 256, B), 256, 0, stream>>>(cls, keys);
  histK<0><<<dim3(256, B), 256, 0, stream>>>(keys, state, hist);
  scanK<0><<<B, 64, 0, stream>>>(hist, state);
  histK<1><<<dim3(256, B), 256, 0, stream>>>(keys, state, hist);
  scanK<1><<<B, 64, 0, stream>>>(hist, state);
  histK<2><<<dim3(256, B), 256, 0, stream>>>(keys, state, hist);
  scanK<2><<<B, 64, 0, stream>>>(hist, state);
  histK<3><<<dim3(256, B), 256, 0, stream>>>(keys, state, hist);
  scanK<3><<<B, 64, 0, stream>>>(hist, state);
  compactK<<<dim3(256, B), 256, 0, stream>>>(keys, state, list, cnt);
  sortK<<<B, 1024, 0, stream>>>(list, cnt, boxes, sel_score, sel_idx, sel_box);
  maskK<<<dim3(KPRE / 256, B), 256, 0, stream>>>(sel_box, mask);
  nmsK<<<B, 64, 0, stream>>>(mask, sel_score, kept_pos, kept_cnt);
  outK<<<dim3((KPOST + 255) / 256, B), 256, 0, stream>>>(cls, sel_score, sel_idx, sel_box,
                                                         kept_pos, kept_cnt, out);
}

// Round 2
// 618.829 us; speedup vs baseline: 1.8075x; 1.8075x over previous
//
#include <hip/hip_runtime.h>
#include <stdint.h>

constexpr int B = 4;
constexpr int N = 262144;
constexpr int C = 10;
constexpr int KPRE = 4096;
constexpr int KPOST = 500;
constexpr float ROI_THR = 0.1f;
constexpr float NMS_THR = 0.01f;
constexpr int CAP = 8192;        // compaction capacity (>= KPRE + boundary ties)
constexpr int MASKW = KPRE / 64; // 64 u64 words per mask row

__device__ __forceinline__ uint32_t f2k(float f) {
  uint32_t u = __float_as_uint(f);
  return (u & 0x80000000u) ? ~u : (u | 0x80000000u);
}
__device__ __forceinline__ float k2f(uint32_t k) {
  uint32_t u = (k & 0x80000000u) ? (k ^ 0x80000000u) : ~k;
  return __uint_as_float(u);
}
__device__ __forceinline__ float sigm(float x) { return 1.0f / (1.0f + expf(-x)); }

// ---------------- K0: scores -> sortable keys (+ fused radix pass-0 histogram) ----------------
__global__ void scoreK(const float* __restrict__ cls, uint32_t* __restrict__ keys,
                       uint32_t* __restrict__ hist) {
  __shared__ uint32_t h[256];
  int b = blockIdx.y;
  for (int i = threadIdx.x; i < 256; i += blockDim.x) h[i] = 0;
  __syncthreads();
  int n = blockIdx.x * blockDim.x + threadIdx.x;
  if (n < N) {
    const float* p = cls + ((size_t)b * N + n) * C;
    float m = sigm(p[0]);
#pragma unroll
    for (int c = 1; c < C; ++c) m = fmaxf(m, sigm(p[c]));
    float s = (m > ROI_THR) ? m : -1.0f;
    uint32_t k = f2k(s);
    keys[(size_t)b * N + n] = k;
    atomicAdd(&h[k >> 24], 1u);
  }
  __syncthreads();
  uint32_t* gh = hist + b * 256; // pass-0 slot
  for (int i = threadIdx.x; i < 256; i += blockDim.x)
    if (h[i]) atomicAdd(&gh[i], h[i]);
}

// ---------------- K1: init ----------------
__global__ void initK(uint32_t* hist, uint32_t* cnt, uint32_t* state, uint32_t* kept_cnt) {
  int t = threadIdx.x;
  for (int i = t; i < 4 * B * 256; i += blockDim.x) hist[i] = 0;
  if (t < B) {
    cnt[t] = 0;
    kept_cnt[t] = 0;
    state[t * 2 + 0] = 0;    // prefix
    state[t * 2 + 1] = KPRE; // remaining rank
  }
}

// ---------------- K2: radix-select histogram pass P (P=1..3) ----------------
template <int P>
__global__ void histK(const uint32_t* __restrict__ keys, const uint32_t* __restrict__ state,
                      uint32_t* __restrict__ hist) {
  __shared__ uint32_t h[256];
  int b = blockIdx.y;
  for (int i = threadIdx.x; i < 256; i += blockDim.x) h[i] = 0;
  __syncthreads();
  uint32_t pref = state[b * 2];
  constexpr int shift = 24 - 8 * P;
  const uint32_t* kb = keys + (size_t)b * N;
  for (int n = blockIdx.x * blockDim.x + threadIdx.x; n < N; n += gridDim.x * blockDim.x) {
    uint32_t k = kb[n];
    bool ok = (((k ^ pref) >> (8 * (4 - P))) == 0);
    if (ok) atomicAdd(&h[(k >> shift) & 255u], 1u);
  }
  __syncthreads();
  uint32_t* gh = hist + (P * B + b) * 256;
  for (int i = threadIdx.x; i < 256; i += blockDim.x)
    if (h[i]) atomicAdd(&gh[i], h[i]);
}

// ---------------- K3: radix-select scan pass P ----------------
template <int P>
__global__ void scanK(const uint32_t* __restrict__ hist, uint32_t* __restrict__ state) {
  int b = blockIdx.x;
  if (threadIdx.x != 0) return;
  const uint32_t* h = hist + (P * B + b) * 256;
  uint32_t R = state[b * 2 + 1];
  uint32_t cum = 0;
  int sel = 0;
  for (int bin = 255; bin >= 0; --bin) {
    uint32_t c = h[bin];
    if (cum + c >= R) { sel = bin; break; }
    cum += c;
  }
  constexpr int shift = 24 - 8 * P;
  state[b * 2 + 0] |= ((uint32_t)sel) << shift;
  state[b * 2 + 1] = R - cum;
}

// ---------------- K4: compact all keys >= T ----------------
__global__ void compactK(const uint32_t* __restrict__ keys, const uint32_t* __restrict__ state,
                         unsigned long long* __restrict__ list, uint32_t* __restrict__ cnt) {
  int b = blockIdx.y;
  uint32_t T = state[b * 2];
  const uint32_t* kb = keys + (size_t)b * N;
  for (int n = blockIdx.x * blockDim.x + threadIdx.x; n < N; n += gridDim.x * blockDim.x) {
    uint32_t k = kb[n];
    if (k >= T) {
      uint32_t pos = atomicAdd(&cnt[b], 1u);
      if (pos < CAP)
        list[(size_t)b * CAP + pos] = ((unsigned long long)k << 32) | (uint32_t)(~(uint32_t)n);
    }
  }
}

// ---------------- K5: bitonic sort (key desc, idx asc) + emit + gather boxes ----------------
__global__ __launch_bounds__(1024) void sortK(const unsigned long long* __restrict__ list,
                                              const uint32_t* __restrict__ cnt,
                                              const float* __restrict__ boxes,
                                              float* __restrict__ sel_score,
                                              uint32_t* __restrict__ sel_idx,
                                              float* __restrict__ sel_box) {
  __shared__ unsigned long long ls[CAP]; // 64 KiB
  int b = blockIdx.x;
  int t = threadIdx.x;
  uint32_t cc = min(cnt[b], (uint32_t)CAP);
  int S = (cc <= (uint32_t)KPRE) ? KPRE : CAP; // sort only what's needed
  for (int i = t; i < S; i += 1024)
    ls[i] = (i < (int)cc) ? list[(size_t)b * CAP + i] : 0ull;
  __syncthreads();
  for (int k = 2; k <= S; k <<= 1) {
    for (int j = k >> 1; j > 0; j >>= 1) {
      for (int i = t; i < S; i += 1024) {
        int l = i ^ j;
        if (l > i) {
          unsigned long long a = ls[i], c = ls[l];
          bool desc = ((i & k) == 0);
          if ((a < c) == desc) { ls[i] = c; ls[l] = a; }
        }
      }
      __syncthreads();
    }
  }
  for (int i = t; i < KPRE; i += 1024) {
    unsigned long long p = ls[i];
    uint32_t key = (uint32_t)(p >> 32);
    uint32_t idx = ~(uint32_t)p;
    float sc;
    if (p == 0ull) { idx = 0; sc = -1.0f; } else sc = k2f(key);
    sel_score[b * KPRE + i] = sc;
    sel_idx[b * KPRE + i] = idx;
    const float* src = boxes + ((size_t)b * N + idx) * 7;
    float* dst = sel_box + ((size_t)b * KPRE + i) * 8;
#pragma unroll
    for (int c7 = 0; c7 < 7; ++c7) dst[c7] = src[c7];
    dst[7] = 0.f;
  }
}

// ---------------- K6: pairwise IoU suppression bitmask (2D tiled) ----------------
// grid: (i_tiles=16, words=64, B); block: 256 threads, thread t owns row i = bi*256+t,
// word w = blockIdx.y (j in [w*64, w*64+64)). 64 j-boxes staged in LDS, broadcast reads.
__global__ void maskK(const float* __restrict__ sel_box, unsigned long long* __restrict__ mask) {
  int b = blockIdx.z;
  int bi = blockIdx.x;
  int w = blockIdx.y;
  int t = threadIdx.x;
  int i = bi * 256 + t;
  int j0 = w * 64;
  unsigned long long* dst = mask + ((size_t)b * KPRE + i) * MASKW + w;
  if (j0 + 63 <= bi * 256) { // whole tile is j <= i: no suppression bits
    *dst = 0ull;
    return;
  }
  __shared__ float jx1[64], jx2[64], jy1[64], jy2[64], ja[64];
  if (t < 64) {
    const float4* bj = (const float4*)(sel_box + ((size_t)b * KPRE + j0 + t) * 8);
    float4 lo = bj[0], hi = bj[1];
    float xj = lo.x, yj = lo.y, dxj = lo.w, dyj = hi.x;
    float hxj = __fmul_rn(dxj, 0.5f), hyj = __fmul_rn(dyj, 0.5f);
    jx1[t] = __fsub_rn(xj, hxj);
    jx2[t] = __fadd_rn(xj, hxj);
    jy1[t] = __fsub_rn(yj, hyj);
    jy2[t] = __fadd_rn(yj, hyj);
    ja[t] = __fmul_rn(dxj, dyj);
  }
  __syncthreads();
  const float4* myb = (const float4*)(sel_box + ((size_t)b * KPRE + i) * 8);
  float4 lo = myb[0], hi = myb[1];
  float x = lo.x, y = lo.y, dx = lo.w, dy = hi.x;
  float hx = __fmul_rn(dx, 0.5f), hy = __fmul_rn(dy, 0.5f);
  float x1i = __fsub_rn(x, hx), x2i = __fadd_rn(x, hx);
  float y1i = __fsub_rn(y, hy), y2i = __fadd_rn(y, hy);
  float ai = __fmul_rn(dx, dy);
  unsigned long long wacc = 0ull;
#pragma unroll 16
  for (int jj = 0; jj < 64; ++jj) {
    int j = j0 + jj;
    float xx1 = fmaxf(x1i, jx1[jj]);
    float xx2 = fminf(x2i, jx2[jj]);
    float yy1 = fmaxf(y1i, jy1[jj]);
    float yy2 = fminf(y2i, jy2[jj]);
    float ix = fmaxf(__fsub_rn(xx2, xx1), 0.0f);
    float iy = fmaxf(__fsub_rn(yy2, yy1), 0.0f);
    float inter = __fmul_rn(ix, iy);
    float uni = __fsub_rn(__fadd_rn(ai, ja[jj]), inter);
    float iou = inter / fmaxf(uni, 1e-6f);
    bool sup = (iou > NMS_THR) && (j > i);
    wacc |= ((unsigned long long)(sup ? 1u : 0u)) << jj;
  }
  *dst = wacc;
}

// ---------------- K7: serial greedy NMS scan (1 wave / batch) ----------------
__global__ void nmsK(const unsigned long long* __restrict__ mask,
                     const float* __restrict__ sel_score,
                     uint32_t* __restrict__ kept_pos, uint32_t* __restrict__ kept_cnt) {
  int b = blockIdx.x;
  int t = threadIdx.x; // 0..63, lane t owns bitmask word t
  unsigned long long cand = 0ull;
  for (int k = 0; k < 64; ++k) {
    float s = sel_score[b * KPRE + k * 64 + t];
    unsigned long long bal = __ballot(s > ROI_THR);
    if (t == k) cand = bal;
  }
  unsigned long long remv = 0ull;
  const unsigned long long* mb = mask + (size_t)b * KPRE * MASKW;
  constexpr int D = 16;
  unsigned long long r[D];
#pragma unroll
  for (int d = 0; d < D; ++d) r[d] = mb[(size_t)d * MASKW + t];
  int kc = 0;
  for (int i0 = 0; i0 < KPRE; i0 += D) {
#pragma unroll
    for (int d = 0; d < D; ++d) {
      int i = i0 + d;
      int w = i >> 6, bit = i & 63;
      unsigned long long g = cand & ~remv;
      uint32_t half = (bit < 32) ? (uint32_t)g : (uint32_t)(g >> 32);
      uint32_t gw = (uint32_t)__shfl((int)half, w, 64);
      if ((gw >> (bit & 31)) & 1u) {
        remv |= r[d];
        if (t == 0 && kc < KPOST) kept_pos[b * KPOST + kc] = i;
        kc++;
      }
      int nx = i + D;
      if (nx < KPRE) r[d] = mb[(size_t)nx * MASKW + t];
    }
    if (kc >= KPOST) break;
  }
  if (t == 0) kept_cnt[b] = (uint32_t)min(kc, KPOST);
}

// ---------------- K8: emit outputs ----------------
__global__ void outK(const float* __restrict__ cls,
                     const float* __restrict__ sel_score, const uint32_t* __restrict__ sel_idx,
                     const float* __restrict__ sel_box,
                     const uint32_t* __restrict__ kept_pos, const uint32_t* __restrict__ kept_cnt,
                     float* __restrict__ out) {
  int b = blockIdx.y;
  int s = blockIdx.x * blockDim.x + threadIdx.x;
  if (s >= KPOST) return;
  float* oS = out;                             // (B, KPOST)
  float* oB = out + B * KPOST;                 // (B, KPOST, 7)
  float* oL = out + B * KPOST + B * KPOST * 7; // (B, KPOST)
  uint32_t kcnt = kept_cnt[b];
  if (s < (int)kcnt) {
    uint32_t pos = kept_pos[b * KPOST + s];
    oS[b * KPOST + s] = sel_score[b * KPRE + pos];
    const float* box = sel_box + ((size_t)b * KPRE + pos) * 8;
    float* dst = oB + ((size_t)b * KPOST + s) * 7;
#pragma unroll
    for (int c = 0; c < 7; ++c) dst[c] = box[c];
    uint32_t idx = sel_idx[b * KPRE + pos];
    const float* p = cls + ((size_t)b * N + idx) * C;
    float bestv = sigm(p[0]);
    int bestc = 0;
#pragma unroll
    for (int c = 1; c < C; ++c) {
      float v = sigm(p[c]);
      if (v > bestv) { bestv = v; bestc = c; }
    }
    oL[b * KPOST + s] = (float)bestc;
  } else {
    oS[b * KPOST + s] = 0.0f;
    float* dst = oB + ((size_t)b * KPOST + s) * 7;
#pragma unroll
    for (int c = 0; c < 7; ++c) dst[c] = 0.0f;
    oL[b * KPOST + s] = -1.0f;
  }
}

__global__ void sentinelK(float* out, int n) {
  int i = blockIdx.x * blockDim.x + threadIdx.x;
  if (i < n) out[i] = 1337.0f;
}

extern "C" void kernel_launch(void* const* d_in, const int* in_sizes, int n_in,
                              void* d_out, int out_size, void* d_ws, size_t ws_size,
                              hipStream_t stream) {
  const float* cls = (const float*)d_in[0];
  const float* boxes = (const float*)d_in[1];
  float* out = (float*)d_out;

  char* ws = (char*)d_ws;
  size_t off = 0;
  auto alloc = [&](size_t bytes) -> void* {
    void* p = ws + off;
    off = (off + bytes + 255) & ~(size_t)255;
    return p;
  };
  unsigned long long* mask = (unsigned long long*)alloc((size_t)B * KPRE * MASKW * 8);
  unsigned long long* list = (unsigned long long*)alloc((size_t)B * CAP * 8);
  uint32_t* keys = (uint32_t*)alloc((size_t)B * N * 4);
  float* sel_box = (float*)alloc((size_t)B * KPRE * 8 * 4);
  float* sel_score = (float*)alloc((size_t)B * KPRE * 4);
  uint32_t* sel_idx = (uint32_t*)alloc((size_t)B * KPRE * 4);
  uint32_t* hist = (uint32_t*)alloc(4 * B * 256 * 4);
  uint32_t* state = (uint32_t*)alloc(B * 2 * 4);
  uint32_t* cnt = (uint32_t*)alloc(B * 4);
  uint32_t* kept_pos = (uint32_t*)alloc(B * KPOST * 4);
  uint32_t* kept_cnt = (uint32_t*)alloc(B * 4);

  if (off > ws_size) {
    sentinelK<<<dim3((out_size + 255) / 256), 256, 0, stream>>>(out, out_size);
    return;
  }

  initK<<<1, 256, 0, stream>>>(hist, cnt, state, kept_cnt);
  scoreK<<<dim3(N / 256, B), 256, 0, stream>>>(cls, keys, hist);
  scanK<0><<<B, 64, 0, stream>>>(hist, state);
  histK<1><<<dim3(256, B), 256, 0, stream>>>(keys, state, hist);
  scanK<1><<<B, 64, 0, stream>>>(hist, state);
  histK<2><<<dim3(256, B), 256, 0, stream>>>(keys, state, hist);
  scanK<2><<<B, 64, 0, stream>>>(hist, state);
  histK<3><<<dim3(256, B), 256, 0, stream>>>(keys, state, hist);
  scanK<3><<<B, 64, 0, stream>>>(hist, state);
  compactK<<<dim3(256, B), 256, 0, stream>>>(keys, state, list, cnt);
  sortK<<<B, 1024, 0, stream>>>(list, cnt, boxes, sel_score, sel_idx, sel_box);
  maskK<<<dim3(16, 64, B), 256, 0, stream>>>(sel_box, mask);
  nmsK<<<B, 64, 0, stream>>>(mask, sel_score, kept_pos, kept_cnt);
  outK<<<dim3((KPOST + 255) / 256, B), 256, 0, stream>>>(cls, sel_score, sel_idx, sel_box,
                                                         kept_pos, kept_cnt, out);
}

// Round 3
// 433.048 us; speedup vs baseline: 2.5830x; 1.4290x over previous
//
#include <hip/hip_runtime.h>
#include <stdint.h>

constexpr int B = 4;
constexpr int N = 262144;
constexpr int C = 10;
constexpr int KPRE = 4096;
constexpr int KPOST = 500;
constexpr float ROI_THR = 0.1f;
constexpr float NMS_THR = 0.01f;
constexpr int CAP = 8192;        // compaction capacity (>= KPRE + boundary ties)
constexpr int MASKW = KPRE / 64; // 64 u64 words per mask row

__device__ __forceinline__ uint32_t f2k(float f) {
  uint32_t u = __float_as_uint(f);
  return (u & 0x80000000u) ? ~u : (u | 0x80000000u);
}
__device__ __forceinline__ float k2f(uint32_t k) {
  uint32_t u = (k & 0x80000000u) ? (k ^ 0x80000000u) : ~k;
  return __uint_as_float(u);
}
__device__ __forceinline__ float sigm(float x) { return 1.0f / (1.0f + expf(-x)); }

__device__ __forceinline__ void async_lds16(const void* g, void* l) {
  __builtin_amdgcn_global_load_lds((const __attribute__((address_space(1))) void*)g,
                                   (__attribute__((address_space(3))) void*)l, 16, 0, 0);
}

// ---------------- K0: scores -> sortable keys (+ fused radix pass-0 histogram) ----------------
__global__ void scoreK(const float* __restrict__ cls, uint32_t* __restrict__ keys,
                       uint32_t* __restrict__ hist) {
  __shared__ uint32_t h[256];
  int b = blockIdx.y;
  for (int i = threadIdx.x; i < 256; i += blockDim.x) h[i] = 0;
  __syncthreads();
  int n = blockIdx.x * blockDim.x + threadIdx.x;
  if (n < N) {
    const float* p = cls + ((size_t)b * N + n) * C;
    float m = sigm(p[0]);
#pragma unroll
    for (int c = 1; c < C; ++c) m = fmaxf(m, sigm(p[c]));
    float s = (m > ROI_THR) ? m : -1.0f;
    uint32_t k = f2k(s);
    keys[(size_t)b * N + n] = k;
    atomicAdd(&h[k >> 24], 1u);
  }
  __syncthreads();
  uint32_t* gh = hist + b * 256; // pass-0 slot
  for (int i = threadIdx.x; i < 256; i += blockDim.x)
    if (h[i]) atomicAdd(&gh[i], h[i]);
}

// ---------------- K1: init ----------------
__global__ void initK(uint32_t* hist, uint32_t* cnt, uint32_t* state, uint32_t* kept_cnt) {
  int t = threadIdx.x;
  for (int i = t; i < 4 * B * 256; i += blockDim.x) hist[i] = 0;
  if (t < B) {
    cnt[t] = 0;
    kept_cnt[t] = 0;
    state[t * 2 + 0] = 0;    // prefix
    state[t * 2 + 1] = KPRE; // remaining rank
  }
}

// ---------------- K2: radix-select histogram pass P (P=1..3) ----------------
template <int P>
__global__ void histK(const uint32_t* __restrict__ keys, const uint32_t* __restrict__ state,
                      uint32_t* __restrict__ hist) {
  __shared__ uint32_t h[256];
  int b = blockIdx.y;
  for (int i = threadIdx.x; i < 256; i += blockDim.x) h[i] = 0;
  __syncthreads();
  uint32_t pref = state[b * 2];
  constexpr int shift = 24 - 8 * P;
  const uint32_t* kb = keys + (size_t)b * N;
  for (int n = blockIdx.x * blockDim.x + threadIdx.x; n < N; n += gridDim.x * blockDim.x) {
    uint32_t k = kb[n];
    bool ok = (((k ^ pref) >> (8 * (4 - P))) == 0);
    if (ok) atomicAdd(&h[(k >> shift) & 255u], 1u);
  }
  __syncthreads();
  uint32_t* gh = hist + (P * B + b) * 256;
  for (int i = threadIdx.x; i < 256; i += blockDim.x)
    if (h[i]) atomicAdd(&gh[i], h[i]);
}

// ---------------- K3: radix-select scan pass P ----------------
template <int P>
__global__ void scanK(const uint32_t* __restrict__ hist, uint32_t* __restrict__ state) {
  int b = blockIdx.x;
  if (threadIdx.x != 0) return;
  const uint32_t* h = hist + (P * B + b) * 256;
  uint32_t R = state[b * 2 + 1];
  uint32_t cum = 0;
  int sel = 0;
  for (int bin = 255; bin >= 0; --bin) {
    uint32_t c = h[bin];
    if (cum + c >= R) { sel = bin; break; }
    cum += c;
  }
  constexpr int shift = 24 - 8 * P;
  state[b * 2 + 0] |= ((uint32_t)sel) << shift;
  state[b * 2 + 1] = R - cum;
}

// ---------------- K4: compact all keys >= T ----------------
__global__ void compactK(const uint32_t* __restrict__ keys, const uint32_t* __restrict__ state,
                         unsigned long long* __restrict__ list, uint32_t* __restrict__ cnt) {
  int b = blockIdx.y;
  uint32_t T = state[b * 2];
  const uint32_t* kb = keys + (size_t)b * N;
  for (int n = blockIdx.x * blockDim.x + threadIdx.x; n < N; n += gridDim.x * blockDim.x) {
    uint32_t k = kb[n];
    if (k >= T) {
      uint32_t pos = atomicAdd(&cnt[b], 1u);
      if (pos < CAP)
        list[(size_t)b * CAP + pos] = ((unsigned long long)k << 32) | (uint32_t)(~(uint32_t)n);
    }
  }
}

// ---------------- K5: bitonic sort (key desc, idx asc) + emit + gather boxes ----------------
__global__ __launch_bounds__(1024) void sortK(const unsigned long long* __restrict__ list,
                                              const uint32_t* __restrict__ cnt,
                                              const float* __restrict__ boxes,
                                              float* __restrict__ sel_score,
                                              uint32_t* __restrict__ sel_idx,
                                              float* __restrict__ sel_box) {
  __shared__ unsigned long long ls[CAP]; // 64 KiB
  int b = blockIdx.x;
  int t = threadIdx.x;
  uint32_t cc = min(cnt[b], (uint32_t)CAP);
  int S = (cc <= (uint32_t)KPRE) ? KPRE : CAP; // sort only what's needed
  for (int i = t; i < S; i += 1024)
    ls[i] = (i < (int)cc) ? list[(size_t)b * CAP + i] : 0ull;
  __syncthreads();
  for (int k = 2; k <= S; k <<= 1) {
    for (int j = k >> 1; j > 0; j >>= 1) {
      for (int i = t; i < S; i += 1024) {
        int l = i ^ j;
        if (l > i) {
          unsigned long long a = ls[i], c = ls[l];
          bool desc = ((i & k) == 0);
          if ((a < c) == desc) { ls[i] = c; ls[l] = a; }
        }
      }
      __syncthreads();
    }
  }
  for (int i = t; i < KPRE; i += 1024) {
    unsigned long long p = ls[i];
    uint32_t key = (uint32_t)(p >> 32);
    uint32_t idx = ~(uint32_t)p;
    float sc;
    if (p == 0ull) { idx = 0; sc = -1.0f; } else sc = k2f(key);
    sel_score[b * KPRE + i] = sc;
    sel_idx[b * KPRE + i] = idx;
    const float* src = boxes + ((size_t)b * N + idx) * 7;
    float* dst = sel_box + ((size_t)b * KPRE + i) * 8;
#pragma unroll
    for (int c7 = 0; c7 < 7; ++c7) dst[c7] = src[c7];
    dst[7] = 0.f;
  }
}

// ---------------- K6: pairwise IoU suppression bitmask (2D tiled) ----------------
__global__ void maskK(const float* __restrict__ sel_box, unsigned long long* __restrict__ mask) {
  int b = blockIdx.z;
  int bi = blockIdx.x;
  int w = blockIdx.y;
  int t = threadIdx.x;
  int i = bi * 256 + t;
  int j0 = w * 64;
  unsigned long long* dst = mask + ((size_t)b * KPRE + i) * MASKW + w;
  if (j0 + 63 <= bi * 256) { // whole tile is j <= i: no suppression bits
    *dst = 0ull;
    return;
  }
  __shared__ float jx1[64], jx2[64], jy1[64], jy2[64], ja[64];
  if (t < 64) {
    const float4* bj = (const float4*)(sel_box + ((size_t)b * KPRE + j0 + t) * 8);
    float4 lo = bj[0], hi = bj[1];
    float xj = lo.x, yj = lo.y, dxj = lo.w, dyj = hi.x;
    float hxj = __fmul_rn(dxj, 0.5f), hyj = __fmul_rn(dyj, 0.5f);
    jx1[t] = __fsub_rn(xj, hxj);
    jx2[t] = __fadd_rn(xj, hxj);
    jy1[t] = __fsub_rn(yj, hyj);
    jy2[t] = __fadd_rn(yj, hyj);
    ja[t] = __fmul_rn(dxj, dyj);
  }
  __syncthreads();
  const float4* myb = (const float4*)(sel_box + ((size_t)b * KPRE + i) * 8);
  float4 lo = myb[0], hi = myb[1];
  float x = lo.x, y = lo.y, dx = lo.w, dy = hi.x;
  float hx = __fmul_rn(dx, 0.5f), hy = __fmul_rn(dy, 0.5f);
  float x1i = __fsub_rn(x, hx), x2i = __fadd_rn(x, hx);
  float y1i = __fsub_rn(y, hy), y2i = __fadd_rn(y, hy);
  float ai = __fmul_rn(dx, dy);
  unsigned long long wacc = 0ull;
#pragma unroll 16
  for (int jj = 0; jj < 64; ++jj) {
    int j = j0 + jj;
    float xx1 = fmaxf(x1i, jx1[jj]);
    float xx2 = fminf(x2i, jx2[jj]);
    float yy1 = fmaxf(y1i, jy1[jj]);
    float yy2 = fminf(y2i, jy2[jj]);
    float ix = fmaxf(__fsub_rn(xx2, xx1), 0.0f);
    float iy = fmaxf(__fsub_rn(yy2, yy1), 0.0f);
    float inter = __fmul_rn(ix, iy);
    float uni = __fsub_rn(__fadd_rn(ai, ja[jj]), inter);
    float iou = inter / fmaxf(uni, 1e-6f);
    bool sup = (iou > NMS_THR) && (j > i);
    wacc |= ((unsigned long long)(sup ? 1u : 0u)) << jj;
  }
  *dst = wacc;
}

// ---------------- K7: greedy NMS scan, group-parallel (1 wave / batch) ----------------
// Per 64-item group g: lane t holds intra-group word m_t = mask[g*64+t][g] (strictly
// upper-triangular). Transpose via 64 ballots -> T_j ("who kills j"). Serial resolve
// iterates only over killer items via a ballot chain (no shfl in the chain). Row-OR of
// kept items comes from LDS (rows prefetched one group ahead via global_load_lds).
__global__ void nmsK(const unsigned long long* __restrict__ mask,
                     const float* __restrict__ sel_score,
                     uint32_t* __restrict__ kept_pos, uint32_t* __restrict__ kept_cnt) {
  __shared__ unsigned long long lds[2][64][64]; // 64 KiB double buffer
  int b = blockIdx.x;
  int t = threadIdx.x; // lane 0..63; owns remv word t

  // candidate bit per item -> lane w holds word w
  unsigned long long cand = 0ull;
  for (int k = 0; k < 64; ++k) {
    float s = sel_score[b * KPRE + k * 64 + t];
    unsigned long long bal = __ballot(s > ROI_THR);
    if (t == k) cand = bal;
  }

  const unsigned long long* mb = mask + (size_t)b * KPRE * MASKW;
  unsigned long long remv = 0ull;
  int kc = 0;

  // prefetch group g rows (32KB) into lds[buf]: 32 x 1KB chunks, lane reads 16B
  auto prefetch = [&](int g, int buf2) {
    const char* base = (const char*)(mb + (size_t)g * 64 * MASKW);
#pragma unroll
    for (int p = 0; p < 32; ++p)
      async_lds16(base + (size_t)p * 1024 + (size_t)t * 16, &lds[buf2][p * 2][0]);
  };

  prefetch(0, 0);
  for (int g = 0; g < 64; ++g) {
    int buf = g & 1;
    asm volatile("s_waitcnt vmcnt(0)" ::: "memory"); // current buf ready
    if (g + 1 < 64) prefetch(g + 1, buf ^ 1);        // overlap next with processing

    unsigned long long cw = cand & ~remv;
    unsigned long long aw = (unsigned long long)__shfl((long long)cw, g, 64);
    if (aw) {
      unsigned long long m = lds[buf][t][g]; // who I kill (intra-group, bits > t)
      // transpose: T = who kills me
      unsigned long long T = 0ull;
#pragma unroll
      for (int j = 0; j < 64; ++j) {
        unsigned long long bj = __ballot(((m >> j) & 1ull) != 0ull);
        if (t == j) T = bj;
      }
      unsigned long long K = __ballot((m & aw) != 0ull); // killers among candidates
      unsigned long long alive = aw;
      bool deadf = ((aw >> t) & 1ull) == 0ull;
      unsigned long long rem = aw & K;
      while (rem) {
        int s = __ffsll(rem) - 1;
        rem &= rem - 1ull;
        if ((alive >> s) & 1ull) { // s is final-alive here
          deadf = deadf || (((T >> s) & 1ull) != 0ull);
          alive = __ballot(!deadf);
          rem &= alive;
        }
      }
      // record kept (in order)
      int grp = __popcll(alive);
      if ((alive >> t) & 1ull) {
        int rank = __popcll(alive & ((1ull << t) - 1ull));
        if (kc + rank < KPOST) kept_pos[b * KPOST + kc + rank] = g * 64 + t;
      }
      // OR rows of kept items into remv (masked unconditional, LDS pipelined)
      unsigned long long acc = 0ull;
#pragma unroll
      for (int s2 = 0; s2 < 64; ++s2) {
        unsigned long long bit = (alive >> s2) & 1ull;
        acc |= lds[buf][s2][t] & (0ull - bit);
      }
      remv |= acc;
      kc += grp;
      if (kc >= KPOST) break;
    }
  }
  asm volatile("s_waitcnt vmcnt(0)" ::: "memory"); // drain any in-flight prefetch
  if (t == 0) kept_cnt[b] = (uint32_t)min(kc, KPOST);
}

// ---------------- K8: emit outputs ----------------
__global__ void outK(const float* __restrict__ cls,
                     const float* __restrict__ sel_score, const uint32_t* __restrict__ sel_idx,
                     const float* __restrict__ sel_box,
                     const uint32_t* __restrict__ kept_pos, const uint32_t* __restrict__ kept_cnt,
                     float* __restrict__ out) {
  int b = blockIdx.y;
  int s = blockIdx.x * blockDim.x + threadIdx.x;
  if (s >= KPOST) return;
  float* oS = out;                             // (B, KPOST)
  float* oB = out + B * KPOST;                 // (B, KPOST, 7)
  float* oL = out + B * KPOST + B * KPOST * 7; // (B, KPOST)
  uint32_t kcnt = kept_cnt[b];
  if (s < (int)kcnt) {
    uint32_t pos = kept_pos[b * KPOST + s];
    oS[b * KPOST + s] = sel_score[b * KPRE + pos];
    const float* box = sel_box + ((size_t)b * KPRE + pos) * 8;
    float* dst = oB + ((size_t)b * KPOST + s) * 7;
#pragma unroll
    for (int c = 0; c < 7; ++c) dst[c] = box[c];
    uint32_t idx = sel_idx[b * KPRE + pos];
    const float* p = cls + ((size_t)b * N + idx) * C;
    float bestv = sigm(p[0]);
    int bestc = 0;
#pragma unroll
    for (int c = 1; c < C; ++c) {
      float v = sigm(p[c]);
      if (v > bestv) { bestv = v; bestc = c; }
    }
    oL[b * KPOST + s] = (float)bestc;
  } else {
    oS[b * KPOST + s] = 0.0f;
    float* dst = oB + ((size_t)b * KPOST + s) * 7;
#pragma unroll
    for (int c = 0; c < 7; ++c) dst[c] = 0.0f;
    oL[b * KPOST + s] = -1.0f;
  }
}

__global__ void sentinelK(float* out, int n) {
  int i = blockIdx.x * blockDim.x + threadIdx.x;
  if (i < n) out[i] = 1337.0f;
}

extern "C" void kernel_launch(void* const* d_in, const int* in_sizes, int n_in,
                              void* d_out, int out_size, void* d_ws, size_t ws_size,
                              hipStream_t stream) {
  const float* cls = (const float*)d_in[0];
  const float* boxes = (const float*)d_in[1];
  float* out = (float*)d_out;

  char* ws = (char*)d_ws;
  size_t off = 0;
  auto alloc = [&](size_t bytes) -> void* {
    void* p = ws + off;
    off = (off + bytes + 255) & ~(size_t)255;
    return p;
  };
  unsigned long long* mask = (unsigned long long*)alloc((size_t)B * KPRE * MASKW * 8);
  unsigned long long* list = (unsigned long long*)alloc((size_t)B * CAP * 8);
  uint32_t* keys = (uint32_t*)alloc((size_t)B * N * 4);
  float* sel_box = (float*)alloc((size_t)B * KPRE * 8 * 4);
  float* sel_score = (float*)alloc((size_t)B * KPRE * 4);
  uint32_t* sel_idx = (uint32_t*)alloc((size_t)B * KPRE * 4);
  uint32_t* hist = (uint32_t*)alloc(4 * B * 256 * 4);
  uint32_t* state = (uint32_t*)alloc(B * 2 * 4);
  uint32_t* cnt = (uint32_t*)alloc(B * 4);
  uint32_t* kept_pos = (uint32_t*)alloc(B * KPOST * 4);
  uint32_t* kept_cnt = (uint32_t*)alloc(B * 4);

  if (off > ws_size) {
    sentinelK<<<dim3((out_size + 255) / 256), 256, 0, stream>>>(out, out_size);
    return;
  }

  initK<<<1, 256, 0, stream>>>(hist, cnt, state, kept_cnt);
  scoreK<<<dim3(N / 256, B), 256, 0, stream>>>(cls, keys, hist);
  scanK<0><<<B, 64, 0, stream>>>(hist, state);
  histK<1><<<dim3(256, B), 256, 0, stream>>>(keys, state, hist);
  scanK<1><<<B, 64, 0, stream>>>(hist, state);
  histK<2><<<dim3(256, B), 256, 0, stream>>>(keys, state, hist);
  scanK<2><<<B, 64, 0, stream>>>(hist, state);
  histK<3><<<dim3(256, B), 256, 0, stream>>>(keys, state, hist);
  scanK<3><<<B, 64, 0, stream>>>(hist, state);
  compactK<<<dim3(256, B), 256, 0, stream>>>(keys, state, list, cnt);
  sortK<<<B, 1024, 0, stream>>>(list, cnt, boxes, sel_score, sel_idx, sel_box);
  maskK<<<dim3(16, 64, B), 256, 0, stream>>>(sel_box, mask);
  nmsK<<<B, 64, 0, stream>>>(mask, sel_score, kept_pos, kept_cnt);
  outK<<<dim3((KPOST + 255) / 256, B), 256, 0, stream>>>(cls, sel_score, sel_idx, sel_box,
                                                         kept_pos, kept_cnt, out);
}